// Round 1
// baseline (229.669 us; speedup 1.0000x reference)
//
#include <hip/hip_runtime.h>
#include <hip/hip_bf16.h>
#include <stdint.h>

// ---------- types ----------
typedef __attribute__((ext_vector_type(8))) __bf16 bf16x8;
typedef __attribute__((ext_vector_type(4))) float f32x4;

__device__ __forceinline__ unsigned short f2b(float f) {
    return __builtin_bit_cast(unsigned short, __float2bfloat16(f));
}

// async global -> LDS, 16B per lane (wave-uniform base + lane*16 dest order)
__device__ __forceinline__ void gload_lds16(const void* g, void* l) {
    __builtin_amdgcn_global_load_lds(
        (__attribute__((address_space(1))) void*)(uintptr_t)g,
        (__attribute__((address_space(3))) void*)l,
        16, 0, 0);
}

#define MFMA16(a, b, c) __builtin_amdgcn_mfma_f32_16x16x32_bf16((a), (b), (c), 0, 0, 0)

// ---------- constants ----------
// B=8192, S=39, A=4, D_IN=43 (pad 64), F=1024, E=8, C=10

// ---------- prep: SA pack + mixture weights ----------
__global__ void k_prep_sa(const float* __restrict__ state, const float* __restrict__ action,
                          const int* __restrict__ c, const float* __restrict__ Wte,
                          unsigned short* __restrict__ SA, float* __restrict__ wmix, int B) {
    int b = blockIdx.x * 256 + threadIdx.x;
    if (b >= B) return;
    unsigned short* row = SA + (size_t)b * 64;
#pragma unroll
    for (int i = 0; i < 39; ++i) row[i] = f2b(state[(size_t)b * 39 + i]);
#pragma unroll
    for (int i = 0; i < 4; ++i) row[39 + i] = f2b(action[(size_t)b * 4 + i]);
#pragma unroll
    for (int i = 43; i < 64; ++i) row[i] = 0;
    int ctx = c[b];
#pragma unroll
    for (int e = 0; e < 8; ++e) wmix[(size_t)b * 8 + e] = Wte[e * 10 + ctx];
}

// ---------- prep: W0 [E,43,1024] f32 -> W0T [E,1024,64] bf16 (n-major, k padded) ----------
__global__ void k_prep_w0t(const float* __restrict__ W0, unsigned short* __restrict__ W0T) {
    int idx = blockIdx.x * 256 + threadIdx.x;   // e*1024 + f
    int e = idx >> 10, f = idx & 1023;
    unsigned short* dst = W0T + (size_t)idx * 64;
#pragma unroll 1
    for (int k = 0; k < 43; ++k) dst[k] = f2b(W0[((size_t)e * 43 + k) * 1024 + f]);
#pragma unroll
    for (int k = 43; k < 64; ++k) dst[k] = 0;
}

// ---------- prep: W1 [E,1024,1024] f32 -> W1T [E,1024(n),1024(k)] bf16 ----------
__global__ void k_prep_w1t(const float* __restrict__ W1, unsigned short* __restrict__ W1T) {
    __shared__ float t[64][65];
    int k0 = blockIdx.x * 64, n0 = blockIdx.y * 64, e = blockIdx.z;
    int tid = threadIdx.x;
    int cl = tid & 63;      // n within tile
    int rg = tid >> 6;      // 0..3
    const float* src = W1 + ((size_t)e * 1024 + k0) * 1024 + n0;
#pragma unroll
    for (int i = 0; i < 16; ++i) {
        int kr = rg * 16 + i;
        t[kr][cl] = src[(size_t)kr * 1024 + cl];
    }
    __syncthreads();
    int nl = tid >> 2, kg = tid & 3;
    unsigned short* dst = W1T + ((size_t)e * 1024 + n0 + nl) * 1024 + k0 + kg * 16;
#pragma unroll
    for (int j = 0; j < 16; ++j) dst[j] = f2b(t[kg * 16 + j][nl]);
}

// ---------- layer 0: H0[e] = relu(SA @ W0T[e]^T + b0[e]), bf16 out ----------
__global__ __launch_bounds__(256, 2)
void k_layer0(const unsigned short* __restrict__ SA,   // [B,64]
              const unsigned short* __restrict__ W0T,  // [E,1024,64]
              const float* __restrict__ b0,            // [E,1024]
              unsigned short* __restrict__ H0,         // [E,Bc,1024]
              int Bc, int row0) {
    __shared__ unsigned short As[128 * 64];
    __shared__ unsigned short Bs[128 * 64];
    int bm = blockIdx.x, bn = blockIdx.y, e = blockIdx.z;
    int tid = threadIdx.x, lane = tid & 63;
    int wv = tid >> 6, wr = wv >> 1, wc = wv & 1;
    int l15 = lane & 15, kg = lane >> 4;

    const char* Ag = (const char*)(SA + (size_t)(row0 + bm * 128) * 64);
    const char* Bg = (const char*)(W0T + ((size_t)e * 1024 + bn * 128) * 64);
#pragma unroll
    for (int it = 0; it < 4; ++it) {
        int off = tid * 16 + it * 4096;   // both tiles are fully contiguous 16KB
        gload_lds16(Ag + off, (char*)As + off);
        gload_lds16(Bg + off, (char*)Bs + off);
    }
    __syncthreads();

    f32x4 acc[4][4];
#pragma unroll
    for (int mi = 0; mi < 4; ++mi)
#pragma unroll
        for (int ni = 0; ni < 4; ++ni) acc[mi][ni] = (f32x4)0.0f;

#pragma unroll
    for (int ks = 0; ks < 2; ++ks) {
        bf16x8 af[4], bv[4];
#pragma unroll
        for (int mi = 0; mi < 4; ++mi)
            af[mi] = *(const bf16x8*)&As[(wr * 64 + mi * 16 + l15) * 64 + ks * 32 + kg * 8];
#pragma unroll
        for (int ni = 0; ni < 4; ++ni)
            bv[ni] = *(const bf16x8*)&Bs[(wc * 64 + ni * 16 + l15) * 64 + ks * 32 + kg * 8];
#pragma unroll
        for (int mi = 0; mi < 4; ++mi)
#pragma unroll
            for (int ni = 0; ni < 4; ++ni)
                acc[mi][ni] = MFMA16(af[mi], bv[ni], acc[mi][ni]);
    }

    float b0v[4];
#pragma unroll
    for (int ni = 0; ni < 4; ++ni)
        b0v[ni] = b0[e * 1024 + bn * 128 + wc * 64 + ni * 16 + l15];
#pragma unroll
    for (int mi = 0; mi < 4; ++mi)
#pragma unroll
        for (int ni = 0; ni < 4; ++ni)
#pragma unroll
            for (int j = 0; j < 4; ++j) {
                int rloc = bm * 128 + wr * 64 + mi * 16 + kg * 4 + j;
                int col = bn * 128 + wc * 64 + ni * 16 + l15;
                float h = fmaxf(acc[mi][ni][j] + b0v[ni], 0.0f);
                H0[((size_t)e * Bc + rloc) * 1024 + col] = f2b(h);
            }
}

// ---------- layer 1 + mixing: mixed = relu(sum_e w[b,e]*relu(H0[e] @ W1T[e]^T + b1[e])) ----------
__global__ __launch_bounds__(256, 2)
void k_layer1_mix(const unsigned short* __restrict__ H0,   // [E,Bc,1024]
                  const unsigned short* __restrict__ W1T,  // [E,1024(n),1024(k)]
                  const float* __restrict__ b1,            // [E,1024]
                  const float* __restrict__ wmix,          // [B,8] (global rows)
                  float* __restrict__ mixed,               // [Bc,1024]
                  int Bc, int row0) {
    __shared__ unsigned short As[128 * 32];
    __shared__ unsigned short Bs[128 * 32];

    int nwg = (Bc / 128) * 8;
    int wg = blockIdx.x;
    // bijective chunked XCD swizzle: all 8 bn-tiles of a bm land on one XCD
    int cpx = nwg >> 3;
    int swz = (wg & 7) * cpx + (wg >> 3);
    int bm = swz >> 3, bn = swz & 7;

    int tid = threadIdx.x, lane = tid & 63;
    int wv = tid >> 6, wr = wv >> 1, wc = wv & 1;
    int l15 = lane & 15, kg = lane >> 4;

    // staging decomposition (16B per lane, 2 issues per buffer per thread)
    int flat0 = tid * 16;
    int flat1 = flat0 + 4096;
    int arow0 = flat0 >> 6, akb0 = flat0 & 63;
    int arow1 = flat1 >> 6, akb1 = flat1 & 63;

    f32x4 mix[4][4];
#pragma unroll
    for (int mi = 0; mi < 4; ++mi)
#pragma unroll
        for (int ni = 0; ni < 4; ++ni) mix[mi][ni] = (f32x4)0.0f;

    for (int e = 0; e < 8; ++e) {
        const char* Ae = (const char*)(H0 + ((size_t)e * Bc + bm * 128) * 1024);
        const char* Be = (const char*)(W1T + ((size_t)e * 1024 + bn * 128) * 1024);

        f32x4 acc[4][4];
#pragma unroll
        for (int mi = 0; mi < 4; ++mi)
#pragma unroll
            for (int ni = 0; ni < 4; ++ni) acc[mi][ni] = (f32x4)0.0f;

        for (int k0 = 0; k0 < 1024; k0 += 32) {
            gload_lds16(Ae + (size_t)arow0 * 2048 + k0 * 2 + akb0, (char*)As + flat0);
            gload_lds16(Ae + (size_t)arow1 * 2048 + k0 * 2 + akb1, (char*)As + flat1);
            gload_lds16(Be + (size_t)arow0 * 2048 + k0 * 2 + akb0, (char*)Bs + flat0);
            gload_lds16(Be + (size_t)arow1 * 2048 + k0 * 2 + akb1, (char*)Bs + flat1);
            __syncthreads();

            bf16x8 af[4], bv[4];
#pragma unroll
            for (int mi = 0; mi < 4; ++mi)
                af[mi] = *(const bf16x8*)&As[(wr * 64 + mi * 16 + l15) * 32 + kg * 8];
#pragma unroll
            for (int ni = 0; ni < 4; ++ni)
                bv[ni] = *(const bf16x8*)&Bs[(wc * 64 + ni * 16 + l15) * 32 + kg * 8];
#pragma unroll
            for (int mi = 0; mi < 4; ++mi)
#pragma unroll
                for (int ni = 0; ni < 4; ++ni)
                    acc[mi][ni] = MFMA16(af[mi], bv[ni], acc[mi][ni]);
            __syncthreads();
        }

        // per-expert epilogue: bias + relu + weighted accumulate into mix
        float b1v[4];
#pragma unroll
        for (int ni = 0; ni < 4; ++ni)
            b1v[ni] = b1[e * 1024 + bn * 128 + wc * 64 + ni * 16 + l15];
#pragma unroll
        for (int mi = 0; mi < 4; ++mi) {
#pragma unroll
            for (int j = 0; j < 4; ++j) {
                int rloc = bm * 128 + wr * 64 + mi * 16 + kg * 4 + j;
                float w = wmix[(size_t)(row0 + rloc) * 8 + e];
#pragma unroll
                for (int ni = 0; ni < 4; ++ni) {
                    float h = fmaxf(acc[mi][ni][j] + b1v[ni], 0.0f);
                    mix[mi][ni][j] += w * h;
                }
            }
        }
    }

    // final relu + store
#pragma unroll
    for (int mi = 0; mi < 4; ++mi)
#pragma unroll
        for (int ni = 0; ni < 4; ++ni)
#pragma unroll
            for (int j = 0; j < 4; ++j) {
                int rloc = bm * 128 + wr * 64 + mi * 16 + kg * 4 + j;
                int col = bn * 128 + wc * 64 + ni * 16 + l15;
                mixed[(size_t)rloc * 1024 + col] = fmaxf(mix[mi][ni][j], 0.0f);
            }
}

// ---------- head: q[b] = mixed[b,:] . Wh[c[b],:] + bh[c[b]] ----------
__global__ void k_head(const float* __restrict__ mixed, const float* __restrict__ Wh,
                       const float* __restrict__ bh, const int* __restrict__ c,
                       float* __restrict__ q, int Bc, int row0) {
    int row = blockIdx.x * 4 + (threadIdx.x >> 6);
    int lane = threadIdx.x & 63;
    if (row >= Bc) return;
    int grow = row0 + row;
    int ctx = c[grow];
    const float4* m4 = (const float4*)(mixed + (size_t)row * 1024);
    const float4* w4 = (const float4*)(Wh + (size_t)ctx * 1024);
    float s = 0.0f;
#pragma unroll
    for (int i = 0; i < 4; ++i) {
        float4 a = m4[lane + i * 64];
        float4 b = w4[lane + i * 64];
        s += a.x * b.x + a.y * b.y + a.z * b.z + a.w * b.w;
    }
#pragma unroll
    for (int off = 32; off > 0; off >>= 1) s += __shfl_down(s, off);
    if (lane == 0) q[grow] = s + bh[ctx];
}

// ---------- host ----------
extern "C" void kernel_launch(void* const* d_in, const int* in_sizes, int n_in,
                              void* d_out, int out_size, void* d_ws, size_t ws_size,
                              hipStream_t stream) {
    const float* state  = (const float*)d_in[0];
    const float* action = (const float*)d_in[1];
    const int*   c      = (const int*)d_in[2];
    const float* W0     = (const float*)d_in[3];
    const float* b0     = (const float*)d_in[4];
    const float* W1     = (const float*)d_in[5];
    const float* b1     = (const float*)d_in[6];
    const float* Wte    = (const float*)d_in[7];
    const float* Wh     = (const float*)d_in[8];
    const float* bh     = (const float*)d_in[9];
    float* q = (float*)d_out;
    int B = in_sizes[2];   // c has B elements

    // workspace layout
    char* p = (char*)d_ws;
    unsigned short* W1T = (unsigned short*)p; p += (size_t)8 * 1024 * 1024 * 2;  // 16 MB
    unsigned short* W0T = (unsigned short*)p; p += (size_t)8 * 1024 * 64 * 2;    // 1 MB
    unsigned short* SA  = (unsigned short*)p; p += (size_t)B * 64 * 2;
    float* wmix         = (float*)p;          p += (size_t)B * 8 * 4;
    size_t fixed = (size_t)(p - (char*)d_ws);

    int Bc = B;
    while (Bc > 128 && fixed + (size_t)Bc * (8 * 1024 * 2 + 1024 * 4) > ws_size) Bc >>= 1;

    unsigned short* H0 = (unsigned short*)p; p += (size_t)8 * Bc * 1024 * 2;
    float* mixed       = (float*)p;

    k_prep_sa<<<(B + 255) / 256, 256, 0, stream>>>(state, action, c, Wte, SA, wmix, B);
    k_prep_w0t<<<(8 * 1024) / 256, 256, 0, stream>>>(W0, W0T);
    k_prep_w1t<<<dim3(16, 16, 8), 256, 0, stream>>>(W1, W1T);

    for (int row0 = 0; row0 < B; row0 += Bc) {
        int nbm = Bc / 128;
        k_layer0<<<dim3(nbm, 8, 8), 256, 0, stream>>>(SA, W0T, b0, H0, Bc, row0);
        k_layer1_mix<<<nbm * 8, 256, 0, stream>>>(H0, W1T, b1, wmix, mixed, Bc, row0);
        k_head<<<(Bc + 3) / 4, 256, 0, stream>>>(mixed, Wh, bh, c, q, Bc, row0);
    }
}